// Round 17
// baseline (184.737 us; speedup 1.0000x reference)
//
#include <hip/hip_runtime.h>
#include <hip/hip_bf16.h>
#include <hip/hip_fp16.h>

#define Bn 8
#define Cn 256
#define Hn 128
#define Wn 128
#define On 256
#define HWn (Hn*Wn)
#define Pn  HWn           // 16384 positions per batch
#define W2ROW 768         // W2 row length (ck)
#define QC  ((size_t)Pn * Cn)

typedef __attribute__((ext_vector_type(8))) short bf16x8;
typedef __attribute__((ext_vector_type(4))) float f32x4;

__device__ __forceinline__ void gload_lds16(const void* g, void* l) {
  __builtin_amdgcn_global_load_lds(
      (__attribute__((address_space(1))) void*)g,
      (__attribute__((address_space(3))) void*)l, 16, 0, 0);
}

__device__ __forceinline__ unsigned short f2bf(float f) {
  unsigned int u = __float_as_uint(f);
  unsigned int r = (u + 0x7fffu + ((u >> 16) & 1u)) >> 16;
  return (unsigned short)r;
}
__device__ __forceinline__ float bf2f(unsigned short u) {
  return __uint_as_float(((unsigned int)u) << 16);
}
__device__ __forceinline__ float h2f(unsigned int u16) {
  return __half2float(__ushort_as_half((unsigned short)u16));
}
__device__ __forceinline__ void bacc(uint4 v, float w, float* f) {
  f[0] += w * __uint_as_float(v.x << 16);
  f[1] += w * __uint_as_float(v.x & 0xffff0000u);
  f[2] += w * __uint_as_float(v.y << 16);
  f[3] += w * __uint_as_float(v.y & 0xffff0000u);
  f[4] += w * __uint_as_float(v.z << 16);
  f[5] += w * __uint_as_float(v.z & 0xffff0000u);
  f[6] += w * __uint_as_float(v.w << 16);
  f[7] += w * __uint_as_float(v.w & 0xffff0000u);
}

// -------- Phase 0: W2[o][k*256+c] = dw[o][c][k]; Woff[j][c] = ow[oc][c][kw], pad->32 rows --------
__global__ __launch_bounds__(256) void k_wprep(
    const float* __restrict__ dw, const float* __restrict__ ow,
    unsigned short* __restrict__ W2, unsigned short* __restrict__ Woff) {
  int r = blockIdx.x;          // 0..799
  int c = threadIdx.x;         // 0..255
  if (r < 768) {
    int k = r >> 8, o = r & 255;
    W2[(size_t)o * W2ROW + k * 256 + c] = f2bf(dw[((size_t)o * Cn + c) * 3 + k]);
  } else {
    int rr = r - 768;          // 0..31
    float v = 0.f;
    if (rr < 18) { int oc = rr / 3, kw = rr - 3 * oc; v = ow[((size_t)oc * Cn + c) * 3 + kw]; }
    Woff[(size_t)rr * Cn + c] = f2bf(v);
  }
}

// -------- Mixed-role kernel: fgemm blocks (first) + transpose blocks (after) --------
// Roles touch disjoint batches; fgemm is latency-bound (4% HBM), transpose is
// HBM-bound (4% VALU) -> co-residency on a CU overlaps the two resource profiles.
__global__ __launch_bounds__(512) void k_mix(
    const float* __restrict__ x,
    unsigned short* __restrict__ xbT,
    const unsigned short* __restrict__ W2,
    const unsigned short* __restrict__ Woff,
    const float* __restrict__ obias,
    float* __restrict__ out,
    int bF0, int nbF, int bT0) {
  __shared__ __attribute__((aligned(16))) char smem[62464];
  int tid = threadIdx.x;
  int nf = nbF << 7;                         // fgemm blocks = nbF*128

  if ((int)blockIdx.x >= nf) {
    // ================= TRANSPOSE role: xbT[b][q][c] <- x[b][c][q] =================
    int tix = blockIdx.x - nf;
    int b = bT0 + (tix >> 8);
    int q0 = (tix & 255) * 64;
    unsigned short (*t)[66] = (unsigned short (*)[66])smem;   // [256][66] = 33.8 KB
    int qq = (tid & 15) * 4;          // q quad
    int cb = tid >> 4;                // 0..31
    const float* xb = x + (size_t)b * Cn * HWn;
    #pragma unroll
    for (int i = 0; i < 8; ++i) {
      int cl = cb + 32 * i;           // 0..255
      float4 v = *(const float4*)(xb + (size_t)cl * HWn + q0 + qq);
      unsigned lo = (unsigned)f2bf(v.x) | ((unsigned)f2bf(v.y) << 16);
      unsigned hi = (unsigned)f2bf(v.z) | ((unsigned)f2bf(v.w) << 16);
      *(unsigned*)&t[cl][qq]     = lo;
      *(unsigned*)&t[cl][qq + 2] = hi;
    }
    __syncthreads();
    unsigned short* dst = xbT + (size_t)b * QC + (size_t)q0 * Cn;
    int c2 = (tid & 127) * 2, qg = tid >> 7;
    #pragma unroll
    for (int j = 0; j < 16; ++j) {
      int ql = j * 4 + qg;
      unsigned u = (unsigned)t[c2][ql] | ((unsigned)t[c2 + 1][ql] << 16);
      *(unsigned*)(dst + (size_t)ql * Cn + c2) = u;
    }
    return;
  }

  // ================= FGEMM role (R16 structure, Goff_lds padded to 34) =================
  int idx = blockIdx.x;
  int z = bF0 + (idx >> 7);
  int pt = idx & 127;
  int ho = (pt & 7) * 16 + (pt >> 3);       // XCD-band swizzle
  const unsigned short* xz = xbT + (size_t)z * QC;

  unsigned short* Qs = (unsigned short*)smem;                       // 32 KB
  unsigned short* Ss = (unsigned short*)(smem + 32768);             // 16 KB
  unsigned short (*Goff_lds)[34] = (unsigned short (*)[34])(smem + 49152); // 8.7 KB, 17-dword stride
  unsigned int (*Sqb)[3]    = (unsigned int (*)[3])(smem + 57856);  // 1.5 KB
  unsigned int (*Swh)[3][2] = (unsigned int (*)[3][2])(smem + 59392); // 3 KB

  int lane = tid & 63, wid = tid >> 6;
  int lg = lane >> 4;
  int q0p = ho * Wn;

  // ---- prologue A: offset conv via MFMA. D[q][j] = sum_c xbT[q0p+q][c] * Woff[j][c] ----
  {
    f32x4 aco0 = (f32x4){0.f, 0.f, 0.f, 0.f};
    f32x4 aco1 = (f32x4){0.f, 0.f, 0.f, 0.f};
    for (int kt = 0; kt < 4; ++kt) {
      int ck0 = kt * 64;
      __syncthreads();
      #pragma unroll
      for (int i = 0; i < 2; ++i) {
        int t2 = tid + i * 512;
        int fo = t2 << 4;
        int row = fo >> 7, slot = (fo >> 4) & 7, ss2 = slot ^ (row & 7);
        gload_lds16(xz + (size_t)(q0p + row) * Cn + ck0 + ss2 * 8, (char*)Qs + fo);
      }
      if (tid < 256) {
        int fo = tid << 4;
        int row = fo >> 7, slot = (fo >> 4) & 7, ss2 = slot ^ (row & 7);
        gload_lds16(Woff + (size_t)row * Cn + ck0 + ss2 * 8, (char*)Ss + fo);
      }
      __syncthreads();
      #pragma unroll
      for (int s = 0; s < 2; ++s) {
        int arow = wid * 16 + (lane & 15);
        int aslot = (s * 4 + lg) ^ (arow & 7);
        bf16x8 af = *(const bf16x8*)((const char*)Qs + arow * 128 + aslot * 16);
        int brow0 = (lane & 15);
        int bslot0 = (s * 4 + lg) ^ (brow0 & 7);
        bf16x8 bf0 = *(const bf16x8*)((const char*)Ss + brow0 * 128 + bslot0 * 16);
        aco0 = __builtin_amdgcn_mfma_f32_16x16x32_bf16(af, bf0, aco0, 0, 0, 0);
        int brow1 = 16 + (lane & 15);
        int bslot1 = (s * 4 + lg) ^ (brow1 & 7);
        bf16x8 bf1 = *(const bf16x8*)((const char*)Ss + brow1 * 128 + bslot1 * 16);
        aco1 = __builtin_amdgcn_mfma_f32_16x16x32_bf16(af, bf1, aco1, 0, 0, 0);
      }
    }
    #pragma unroll
    for (int rr = 0; rr < 4; ++rr) {
      int qrow = wid * 16 + lg * 4 + rr;
      Goff_lds[qrow][(lane & 15)]      = f2bf(aco0[rr]);
      Goff_lds[qrow][16 + (lane & 15)] = f2bf(aco1[rr]);
    }
  }
  __syncthreads();   // Goff_lds ready

  // ---- prologue B: offsets -> packed bilinear tables per (p,k) ----
  if (tid < 384) {
    int k = tid >> 7;                 // 0..2
    int wo = tid & 127;
    float offy = 0.f, offx = 0.f;
    int ocy = 2 * k, ocx = 2 * k + 1;
    if (ocy != 4) {
      float s = obias[ocy];
      #pragma unroll
      for (int kw = 0; kw < 3; ++kw) {
        int col = wo + kw - 1;
        if (col >= 0 && col < Wn)
          s += bf2f(Goff_lds[col][ocy * 3 + kw]);
      }
      offy = s;
    }
    if (ocx != 1) {
      float s = obias[ocx];
      #pragma unroll
      for (int kw = 0; kw < 3; ++kw) {
        int col = wo + kw - 1;
        if (col >= 0 && col < Wn)
          s += bf2f(Goff_lds[col][ocx * 3 + kw]);
      }
      offx = s;
    }
    float py = (float)ho + offy;
    float px = (float)(wo + k - 1) + offx;
    float y0f = floorf(py), x0f = floorf(px);
    float wy = py - y0f, wx = px - x0f;
    int y0 = (int)y0f, x0 = (int)x0f;
    int y1 = y0 + 1, x1 = x0 + 1;
    bool vy0 = (y0 >= 0) && (y0 < Hn), vy1 = (y1 >= 0) && (y1 < Hn);
    bool vx0 = (x0 >= 0) && (x0 < Wn), vx1 = (x1 >= 0) && (x1 < Wn);
    int yc0 = min(max(y0, 0), Hn - 1), yc1 = min(max(y1, 0), Hn - 1);
    int xc0 = min(max(x0, 0), Wn - 1), xc1 = min(max(x1, 0), Wn - 1);
    float w00 = (vy0 && vx0) ? (1.f - wy) * (1.f - wx) : 0.f;
    float w01 = (vy0 && vx1) ? (1.f - wy) * wx : 0.f;
    float w10 = (vy1 && vx0) ? wy * (1.f - wx) : 0.f;
    float w11 = (vy1 && vx1) ? wy * wx : 0.f;
    Sqb[wo][k] = (unsigned)yc0 | ((unsigned)xc0 << 8) | ((unsigned)yc1 << 16) | ((unsigned)xc1 << 24);
    unsigned short h00 = __half_as_ushort(__float2half_rn(w00));
    unsigned short h01 = __half_as_ushort(__float2half_rn(w01));
    unsigned short h10 = __half_as_ushort(__float2half_rn(w10));
    unsigned short h11 = __half_as_ushort(__float2half_rn(w11));
    Swh[wo][k][0] = (unsigned)h00 | ((unsigned)h01 << 16);
    Swh[wo][k][1] = (unsigned)h10 | ((unsigned)h11 << 16);
  }

  int wr = wid >> 1, wc = wid & 1;          // wr: o-quarter, wc: p-half
  int oct = tid & 7, pg = tid >> 3;         // staging: 8 octets x 64 p-groups
  int plA = pg, plB = pg + 64;
  f32x4 acc[4][4];
  #pragma unroll
  for (int m = 0; m < 4; ++m)
    #pragma unroll
    for (int n = 0; n < 4; ++n) acc[m][n] = (f32x4){0.f, 0.f, 0.f, 0.f};

  __syncthreads();   // tables ready

  const char* xzb = (const char*)xz;
  int octo = oct * 16;
  int dsA = plA * 128 + ((oct ^ (plA & 7)) << 4);
  int dsB = plB * 128 + ((oct ^ (plB & 7)) << 4);

  uint4 gA0, gA1, gA2, gA3, gB0, gB1, gB2, gB3;
  unsigned wpa0, wpa1, wpb0, wpb1;

  #define PREF(KT) do {                                                        \
    int kk = (KT) >> 2;                                                        \
    const char* bse = xzb + (((KT) & 3) << 7) + octo;                          \
    unsigned qpA = Sqb[plA][kk], qpB = Sqb[plB][kk];                           \
    wpa0 = Swh[plA][kk][0]; wpa1 = Swh[plA][kk][1];                            \
    wpb0 = Swh[plB][kk][0]; wpb1 = Swh[plB][kk][1];                            \
    int yA0 = (int)(qpA & 255u) << 16, xA0 = (int)((qpA >> 8) & 255u) << 9;    \
    int yA1 = (int)((qpA >> 16) & 255u) << 16, xA1 = (int)(qpA >> 24) << 9;    \
    int yB0 = (int)(qpB & 255u) << 16, xB0 = (int)((qpB >> 8) & 255u) << 9;    \
    int yB1 = (int)((qpB >> 16) & 255u) << 16, xB1 = (int)(qpB >> 24) << 9;    \
    gA0 = *(const uint4*)(bse + yA0 + xA0);                                    \
    gA1 = *(const uint4*)(bse + yA0 + xA1);                                    \
    gA2 = *(const uint4*)(bse + yA1 + xA0);                                    \
    gA3 = *(const uint4*)(bse + yA1 + xA1);                                    \
    gB0 = *(const uint4*)(bse + yB0 + xB0);                                    \
    gB1 = *(const uint4*)(bse + yB0 + xB1);                                    \
    gB2 = *(const uint4*)(bse + yB1 + xB0);                                    \
    gB3 = *(const uint4*)(bse + yB1 + xB1);                                    \
  } while (0)

  PREF(0);

  #pragma unroll
  for (int kt = 0; kt < 12; ++kt) {
    int k = kt >> 2;
    int c0 = (kt & 3) << 6;
    __syncthreads();                        // sync1
    #pragma unroll
    for (int i = 0; i < 4; ++i) {
      int t2 = tid + i * 512;
      int fo = t2 << 4;
      int row = fo >> 7;
      int slot = (fo >> 4) & 7;
      int ss = slot ^ (row & 7);
      gload_lds16(W2 + (size_t)row * W2ROW + k * 256 + c0 + ss * 8, (char*)Qs + fo);
    }
    {
      float f[8] = {0.f, 0.f, 0.f, 0.f, 0.f, 0.f, 0.f, 0.f};
      bacc(gA0, h2f(wpa0 & 0xffffu), f); bacc(gA1, h2f(wpa0 >> 16), f);
      bacc(gA2, h2f(wpa1 & 0xffffu), f); bacc(gA3, h2f(wpa1 >> 16), f);
      uint4 r;
      r.x = (unsigned)f2bf(f[0]) | ((unsigned)f2bf(f[1]) << 16);
      r.y = (unsigned)f2bf(f[2]) | ((unsigned)f2bf(f[3]) << 16);
      r.z = (unsigned)f2bf(f[4]) | ((unsigned)f2bf(f[5]) << 16);
      r.w = (unsigned)f2bf(f[6]) | ((unsigned)f2bf(f[7]) << 16);
      *(uint4*)((char*)Ss + dsA) = r;
    }
    {
      float f[8] = {0.f, 0.f, 0.f, 0.f, 0.f, 0.f, 0.f, 0.f};
      bacc(gB0, h2f(wpb0 & 0xffffu), f); bacc(gB1, h2f(wpb0 >> 16), f);
      bacc(gB2, h2f(wpb1 & 0xffffu), f); bacc(gB3, h2f(wpb1 >> 16), f);
      uint4 r;
      r.x = (unsigned)f2bf(f[0]) | ((unsigned)f2bf(f[1]) << 16);
      r.y = (unsigned)f2bf(f[2]) | ((unsigned)f2bf(f[3]) << 16);
      r.z = (unsigned)f2bf(f[4]) | ((unsigned)f2bf(f[5]) << 16);
      r.w = (unsigned)f2bf(f[6]) | ((unsigned)f2bf(f[7]) << 16);
      *(uint4*)((char*)Ss + dsB) = r;
    }
    __syncthreads();                        // sync2
    if (kt < 11) PREF(kt + 1);
    #pragma unroll
    for (int s = 0; s < 2; ++s) {
      bf16x8 af[4], bfr[4];
      #pragma unroll
      for (int m = 0; m < 4; ++m) {
        int row = wr * 64 + m * 16 + (lane & 15);
        int slot = (s * 4 + lg) ^ (row & 7);
        af[m] = *(const bf16x8*)((const char*)Qs + row * 128 + slot * 16);
      }
      #pragma unroll
      for (int n = 0; n < 4; ++n) {
        int row = wc * 64 + n * 16 + (lane & 15);
        int slot = (s * 4 + lg) ^ (row & 7);
        bfr[n] = *(const bf16x8*)((const char*)Ss + row * 128 + slot * 16);
      }
      #pragma unroll
      for (int m = 0; m < 4; ++m)
        #pragma unroll
        for (int n = 0; n < 4; ++n)
          acc[m][n] = __builtin_amdgcn_mfma_f32_16x16x32_bf16(af[m], bfr[n], acc[m][n], 0, 0, 0);
    }
  }
  #undef PREF

  float* ob_ = out + (size_t)z * On * Pn + (size_t)ho * Wn;
  #pragma unroll
  for (int m = 0; m < 4; ++m)
    #pragma unroll
    for (int n = 0; n < 4; ++n)
      #pragma unroll
      for (int rr = 0; rr < 4; ++rr) {
        int o = wr * 64 + m * 16 + lg * 4 + rr;
        int pc = wc * 64 + n * 16 + (lane & 15);
        ob_[(size_t)o * Pn + pc] = acc[m][n][rr];
      }
}

extern "C" void kernel_launch(void* const* d_in, const int* in_sizes, int n_in,
                              void* d_out, int out_size, void* d_ws, size_t ws_size,
                              hipStream_t stream) {
  const float* x  = (const float*)d_in[0];
  const float* ow = (const float*)d_in[1];
  const float* ob = (const float*)d_in[2];
  const float* dw = (const float*)d_in[3];
  float* out = (float*)d_out;

  char* ws = (char*)d_ws;
  size_t w2_bytes   = (size_t)On * W2ROW * 2;           // 384 KB
  size_t woff_bytes = (size_t)32 * Cn * 2;              // 16 KB
  size_t w2_al   = (w2_bytes + 255) & ~(size_t)255;
  size_t woff_al = (woff_bytes + 255) & ~(size_t)255;

  unsigned short* W2   = (unsigned short*)ws;
  unsigned short* Woff = (unsigned short*)(ws + w2_al);
  unsigned short* xbT  = (unsigned short*)(ws + w2_al + woff_al);
  (void)ws_size;

  k_wprep<<<800, 256, 0, stream>>>(dw, ow, W2, Woff);
  // Software-pipelined batch waves: fgemm(b-2,b-1) || transpose(b,b+1)
  for (int s = 0; s <= 4; ++s) {
    int nbF = (s >= 1) ? 2 : 0;             // s=1..4: fgemm batches 2s-2,2s-1
    int bF0 = (s - 1) * 2;
    int nbT = (s <= 3) ? 2 : 0;             // s=0..3: transpose batches 2s,2s+1
    int bT0 = s * 2;
    int grid = nbF * 128 + nbT * 256;
    k_mix<<<grid, 512, 0, stream>>>(x, xbT, W2, Woff, ob, out, bF0, nbF, bT0);
  }
}

// Round 18
// 168.109 us; speedup vs baseline: 1.0989x; 1.0989x over previous
//
#include <hip/hip_runtime.h>
#include <hip/hip_bf16.h>
#include <hip/hip_fp16.h>

#define Bn 8
#define Cn 256
#define Hn 128
#define Wn 128
#define On 256
#define HWn (Hn*Wn)
#define Pn  HWn           // 16384 positions per batch
#define W2ROW 768         // W2 row length (ck)
#define QC  ((size_t)Pn * Cn)

typedef __attribute__((ext_vector_type(8))) short bf16x8;
typedef __attribute__((ext_vector_type(4))) float f32x4;

__device__ __forceinline__ void gload_lds16(const void* g, void* l) {
  __builtin_amdgcn_global_load_lds(
      (__attribute__((address_space(1))) void*)g,
      (__attribute__((address_space(3))) void*)l, 16, 0, 0);
}

__device__ __forceinline__ unsigned short f2bf(float f) {
  unsigned int u = __float_as_uint(f);
  unsigned int r = (u + 0x7fffu + ((u >> 16) & 1u)) >> 16;
  return (unsigned short)r;
}
__device__ __forceinline__ float bf2f(unsigned short u) {
  return __uint_as_float(((unsigned int)u) << 16);
}
__device__ __forceinline__ float h2f(unsigned int u16) {
  return __half2float(__ushort_as_half((unsigned short)u16));
}
__device__ __forceinline__ void bacc(uint4 v, float w, float* f) {
  f[0] += w * __uint_as_float(v.x << 16);
  f[1] += w * __uint_as_float(v.x & 0xffff0000u);
  f[2] += w * __uint_as_float(v.y << 16);
  f[3] += w * __uint_as_float(v.y & 0xffff0000u);
  f[4] += w * __uint_as_float(v.z << 16);
  f[5] += w * __uint_as_float(v.z & 0xffff0000u);
  f[6] += w * __uint_as_float(v.w << 16);
  f[7] += w * __uint_as_float(v.w & 0xffff0000u);
}

// -------- Phase 0: W2[o][k*256+c] = dw[o][c][k]; Woff[j][c] = ow[oc][c][kw], pad->32 rows --------
__global__ __launch_bounds__(256) void k_wprep(
    const float* __restrict__ dw, const float* __restrict__ ow,
    unsigned short* __restrict__ W2, unsigned short* __restrict__ Woff) {
  int r = blockIdx.x;          // 0..799
  int c = threadIdx.x;         // 0..255
  if (r < 768) {
    int k = r >> 8, o = r & 255;
    W2[(size_t)o * W2ROW + k * 256 + c] = f2bf(dw[((size_t)o * Cn + c) * 3 + k]);
  } else {
    int rr = r - 768;          // 0..31
    float v = 0.f;
    if (rr < 18) { int oc = rr / 3, kw = rr - 3 * oc; v = ow[((size_t)oc * Cn + c) * 3 + kw]; }
    Woff[(size_t)rr * Cn + c] = f2bf(v);
  }
}

// -------- Phase 1: transpose+cast  xbT[z][q][c] bf16 <- x[b][c][q] fp32 (float4 loads) --------
__global__ __launch_bounds__(256) void k_transpose(
    const float* __restrict__ x, unsigned short* __restrict__ xbT) {
  int b = blockIdx.z;
  int q0 = blockIdx.x * 64, c0 = blockIdx.y * 64;
  __shared__ unsigned short t[64][66];
  int tid = threadIdx.x;
  int qq = (tid & 15) * 4;          // q quad within tile
  int cb = tid >> 4;                // 0..15
  const float* xb = x + (size_t)b * Cn * HWn;
  #pragma unroll
  for (int i = 0; i < 4; ++i) {
    int cl = cb + 16 * i;
    float4 v = *(const float4*)(xb + (size_t)(c0 + cl) * HWn + q0 + qq);
    unsigned lo = (unsigned)f2bf(v.x) | ((unsigned)f2bf(v.y) << 16);
    unsigned hi = (unsigned)f2bf(v.z) | ((unsigned)f2bf(v.w) << 16);
    *(unsigned*)&t[cl][qq]     = lo;
    *(unsigned*)&t[cl][qq + 2] = hi;
  }
  __syncthreads();
  unsigned short* dst = xbT + (size_t)b * QC;
  int c2 = (tid & 31) * 2, qg = tid >> 5;
  #pragma unroll
  for (int j = 0; j < 8; ++j) {
    int ql = j * 8 + qg;
    unsigned int u = (unsigned int)t[c2][ql] | ((unsigned int)t[c2 + 1][ql] << 16);
    *(unsigned int*)(dst + (size_t)(q0 + ql) * Cn + c0 + c2) = u;
  }
}

// -------- Phase 2: fused offset-conv + sample + GEMM (R16 structure, Goff_lds padded to 34) --------
__global__ __launch_bounds__(512) void k_fgemm(
    const unsigned short* __restrict__ xbT,
    const unsigned short* __restrict__ W2,
    const unsigned short* __restrict__ Woff,
    const float* __restrict__ obias,
    float* __restrict__ out) {
  int pt = blockIdx.x, z = blockIdx.y;
  int ho = (pt & 7) * 16 + (pt >> 3);       // XCD-band swizzle
  const unsigned short* xz = xbT + (size_t)z * QC;

  __shared__ unsigned short Qs[256 * 64];   // W2 tile [o=256][64ck] swizzled (32 KB)
  __shared__ unsigned short Ss[128 * 64];   // sampled tile [p][64c] swizzled (16 KB)
  __shared__ unsigned short Goff_lds[128][34]; // offset-conv result, 17-dword stride (8.7 KB)
  __shared__ unsigned int Sqb[128][3];      // packed clamped coords yc0|xc0<<8|yc1<<16|xc1<<24
  __shared__ unsigned int Swh[128][3][2];   // 4 fp16 bilinear weights

  int tid = threadIdx.x;
  int lane = tid & 63, wid = tid >> 6;
  int lg = lane >> 4;
  int q0p = ho * Wn;

  // ---- prologue A: offset conv via MFMA. D[q][j] = sum_c xbT[q0p+q][c] * Woff[j][c] ----
  {
    f32x4 aco0 = (f32x4){0.f, 0.f, 0.f, 0.f};
    f32x4 aco1 = (f32x4){0.f, 0.f, 0.f, 0.f};
    for (int kt = 0; kt < 4; ++kt) {
      int ck0 = kt * 64;
      __syncthreads();
      #pragma unroll
      for (int i = 0; i < 2; ++i) {
        int t2 = tid + i * 512;             // 0..1023 -> 128 rows x 128B
        int fo = t2 << 4;
        int row = fo >> 7, slot = (fo >> 4) & 7, ss2 = slot ^ (row & 7);
        gload_lds16(xz + (size_t)(q0p + row) * Cn + ck0 + ss2 * 8, (char*)Qs + fo);
      }
      if (tid < 256) {                      // 32 rows x 128B of Woff
        int fo = tid << 4;
        int row = fo >> 7, slot = (fo >> 4) & 7, ss2 = slot ^ (row & 7);
        gload_lds16(Woff + (size_t)row * Cn + ck0 + ss2 * 8, (char*)Ss + fo);
      }
      __syncthreads();
      #pragma unroll
      for (int s = 0; s < 2; ++s) {
        int arow = wid * 16 + (lane & 15);
        int aslot = (s * 4 + lg) ^ (arow & 7);
        bf16x8 af = *(const bf16x8*)((const char*)Qs + arow * 128 + aslot * 16);
        int brow0 = (lane & 15);
        int bslot0 = (s * 4 + lg) ^ (brow0 & 7);
        bf16x8 bf0 = *(const bf16x8*)((const char*)Ss + brow0 * 128 + bslot0 * 16);
        aco0 = __builtin_amdgcn_mfma_f32_16x16x32_bf16(af, bf0, aco0, 0, 0, 0);
        int brow1 = 16 + (lane & 15);
        int bslot1 = (s * 4 + lg) ^ (brow1 & 7);
        bf16x8 bf1 = *(const bf16x8*)((const char*)Ss + brow1 * 128 + bslot1 * 16);
        aco1 = __builtin_amdgcn_mfma_f32_16x16x32_bf16(af, bf1, aco1, 0, 0, 0);
      }
    }
    #pragma unroll
    for (int rr = 0; rr < 4; ++rr) {
      int qrow = wid * 16 + lg * 4 + rr;
      Goff_lds[qrow][(lane & 15)]      = f2bf(aco0[rr]);
      Goff_lds[qrow][16 + (lane & 15)] = f2bf(aco1[rr]);
    }
  }
  __syncthreads();   // Goff_lds ready

  // ---- prologue B: offsets -> packed bilinear tables per (p,k) ----
  if (tid < 384) {
    int k = tid >> 7;                 // 0..2
    int wo = tid & 127;
    float offy = 0.f, offx = 0.f;
    int ocy = 2 * k, ocx = 2 * k + 1;
    if (ocy != 4) {
      float s = obias[ocy];
      #pragma unroll
      for (int kw = 0; kw < 3; ++kw) {
        int col = wo + kw - 1;
        if (col >= 0 && col < Wn)
          s += bf2f(Goff_lds[col][ocy * 3 + kw]);
      }
      offy = s;
    }
    if (ocx != 1) {
      float s = obias[ocx];
      #pragma unroll
      for (int kw = 0; kw < 3; ++kw) {
        int col = wo + kw - 1;
        if (col >= 0 && col < Wn)
          s += bf2f(Goff_lds[col][ocx * 3 + kw]);
      }
      offx = s;
    }
    float py = (float)ho + offy;
    float px = (float)(wo + k - 1) + offx;
    float y0f = floorf(py), x0f = floorf(px);
    float wy = py - y0f, wx = px - x0f;
    int y0 = (int)y0f, x0 = (int)x0f;
    int y1 = y0 + 1, x1 = x0 + 1;
    bool vy0 = (y0 >= 0) && (y0 < Hn), vy1 = (y1 >= 0) && (y1 < Hn);
    bool vx0 = (x0 >= 0) && (x0 < Wn), vx1 = (x1 >= 0) && (x1 < Wn);
    int yc0 = min(max(y0, 0), Hn - 1), yc1 = min(max(y1, 0), Hn - 1);
    int xc0 = min(max(x0, 0), Wn - 1), xc1 = min(max(x1, 0), Wn - 1);
    float w00 = (vy0 && vx0) ? (1.f - wy) * (1.f - wx) : 0.f;
    float w01 = (vy0 && vx1) ? (1.f - wy) * wx : 0.f;
    float w10 = (vy1 && vx0) ? wy * (1.f - wx) : 0.f;
    float w11 = (vy1 && vx1) ? wy * wx : 0.f;
    Sqb[wo][k] = (unsigned)yc0 | ((unsigned)xc0 << 8) | ((unsigned)yc1 << 16) | ((unsigned)xc1 << 24);
    unsigned short h00 = __half_as_ushort(__float2half_rn(w00));
    unsigned short h01 = __half_as_ushort(__float2half_rn(w01));
    unsigned short h10 = __half_as_ushort(__float2half_rn(w10));
    unsigned short h11 = __half_as_ushort(__float2half_rn(w11));
    Swh[wo][k][0] = (unsigned)h00 | ((unsigned)h01 << 16);
    Swh[wo][k][1] = (unsigned)h10 | ((unsigned)h11 << 16);
  }

  int wr = wid >> 1, wc = wid & 1;          // wr: o-quarter, wc: p-half
  int oct = tid & 7, pg = tid >> 3;         // staging: 8 octets x 64 p-groups
  int plA = pg, plB = pg + 64;
  f32x4 acc[4][4];
  #pragma unroll
  for (int m = 0; m < 4; ++m)
    #pragma unroll
    for (int n = 0; n < 4; ++n) acc[m][n] = (f32x4){0.f, 0.f, 0.f, 0.f};

  __syncthreads();   // tables ready

  const char* xzb = (const char*)xz;
  int octo = oct * 16;
  int dsA = plA * 128 + ((oct ^ (plA & 7)) << 4);
  int dsB = plB * 128 + ((oct ^ (plB & 7)) << 4);

  uint4 gA0, gA1, gA2, gA3, gB0, gB1, gB2, gB3;
  unsigned wpa0, wpa1, wpb0, wpb1;

  #define PREF(KT) do {                                                        \
    int kk = (KT) >> 2;                                                        \
    const char* bse = xzb + (((KT) & 3) << 7) + octo;                          \
    unsigned qpA = Sqb[plA][kk], qpB = Sqb[plB][kk];                           \
    wpa0 = Swh[plA][kk][0]; wpa1 = Swh[plA][kk][1];                            \
    wpb0 = Swh[plB][kk][0]; wpb1 = Swh[plB][kk][1];                            \
    int yA0 = (int)(qpA & 255u) << 16, xA0 = (int)((qpA >> 8) & 255u) << 9;    \
    int yA1 = (int)((qpA >> 16) & 255u) << 16, xA1 = (int)(qpA >> 24) << 9;    \
    int yB0 = (int)(qpB & 255u) << 16, xB0 = (int)((qpB >> 8) & 255u) << 9;    \
    int yB1 = (int)((qpB >> 16) & 255u) << 16, xB1 = (int)(qpB >> 24) << 9;    \
    gA0 = *(const uint4*)(bse + yA0 + xA0);                                    \
    gA1 = *(const uint4*)(bse + yA0 + xA1);                                    \
    gA2 = *(const uint4*)(bse + yA1 + xA0);                                    \
    gA3 = *(const uint4*)(bse + yA1 + xA1);                                    \
    gB0 = *(const uint4*)(bse + yB0 + xB0);                                    \
    gB1 = *(const uint4*)(bse + yB0 + xB1);                                    \
    gB2 = *(const uint4*)(bse + yB1 + xB0);                                    \
    gB3 = *(const uint4*)(bse + yB1 + xB1);                                    \
  } while (0)

  PREF(0);

  #pragma unroll
  for (int kt = 0; kt < 12; ++kt) {
    int k = kt >> 2;
    int c0 = (kt & 3) << 6;
    __syncthreads();                        // sync1: MFMA of kt-1 done; drains prefetched gathers
    #pragma unroll
    for (int i = 0; i < 4; ++i) {
      int t2 = tid + i * 512;               // 0..2047
      int fo = t2 << 4;
      int row = fo >> 7;
      int slot = (fo >> 4) & 7;
      int ss = slot ^ (row & 7);
      gload_lds16(W2 + (size_t)row * W2ROW + k * 256 + c0 + ss * 8, (char*)Qs + fo);
    }
    {
      float f[8] = {0.f, 0.f, 0.f, 0.f, 0.f, 0.f, 0.f, 0.f};
      bacc(gA0, h2f(wpa0 & 0xffffu), f); bacc(gA1, h2f(wpa0 >> 16), f);
      bacc(gA2, h2f(wpa1 & 0xffffu), f); bacc(gA3, h2f(wpa1 >> 16), f);
      uint4 r;
      r.x = (unsigned)f2bf(f[0]) | ((unsigned)f2bf(f[1]) << 16);
      r.y = (unsigned)f2bf(f[2]) | ((unsigned)f2bf(f[3]) << 16);
      r.z = (unsigned)f2bf(f[4]) | ((unsigned)f2bf(f[5]) << 16);
      r.w = (unsigned)f2bf(f[6]) | ((unsigned)f2bf(f[7]) << 16);
      *(uint4*)((char*)Ss + dsA) = r;
    }
    {
      float f[8] = {0.f, 0.f, 0.f, 0.f, 0.f, 0.f, 0.f, 0.f};
      bacc(gB0, h2f(wpb0 & 0xffffu), f); bacc(gB1, h2f(wpb0 >> 16), f);
      bacc(gB2, h2f(wpb1 & 0xffffu), f); bacc(gB3, h2f(wpb1 >> 16), f);
      uint4 r;
      r.x = (unsigned)f2bf(f[0]) | ((unsigned)f2bf(f[1]) << 16);
      r.y = (unsigned)f2bf(f[2]) | ((unsigned)f2bf(f[3]) << 16);
      r.z = (unsigned)f2bf(f[4]) | ((unsigned)f2bf(f[5]) << 16);
      r.w = (unsigned)f2bf(f[6]) | ((unsigned)f2bf(f[7]) << 16);
      *(uint4*)((char*)Ss + dsB) = r;
    }
    __syncthreads();                        // sync2: A landed + B written
    if (kt < 11) PREF(kt + 1);
    #pragma unroll
    for (int s = 0; s < 2; ++s) {
      bf16x8 af[4], bfr[4];
      #pragma unroll
      for (int m = 0; m < 4; ++m) {
        int row = wr * 64 + m * 16 + (lane & 15);   // o-row 0..255
        int slot = (s * 4 + lg) ^ (row & 7);
        af[m] = *(const bf16x8*)((const char*)Qs + row * 128 + slot * 16);
      }
      #pragma unroll
      for (int n = 0; n < 4; ++n) {
        int row = wc * 64 + n * 16 + (lane & 15);   // p-row 0..127
        int slot = (s * 4 + lg) ^ (row & 7);
        bfr[n] = *(const bf16x8*)((const char*)Ss + row * 128 + slot * 16);
      }
      #pragma unroll
      for (int m = 0; m < 4; ++m)
        #pragma unroll
        for (int n = 0; n < 4; ++n)
          acc[m][n] = __builtin_amdgcn_mfma_f32_16x16x32_bf16(af[m], bfr[n], acc[m][n], 0, 0, 0);
    }
  }
  #undef PREF

  // C write: D row = o (A-operand), col = p
  float* ob_ = out + (size_t)z * On * Pn + (size_t)ho * Wn;
  #pragma unroll
  for (int m = 0; m < 4; ++m)
    #pragma unroll
    for (int n = 0; n < 4; ++n)
      #pragma unroll
      for (int rr = 0; rr < 4; ++rr) {
        int o = wr * 64 + m * 16 + lg * 4 + rr;
        int pc = wc * 64 + n * 16 + (lane & 15);
        ob_[(size_t)o * Pn + pc] = acc[m][n][rr];
      }
}

extern "C" void kernel_launch(void* const* d_in, const int* in_sizes, int n_in,
                              void* d_out, int out_size, void* d_ws, size_t ws_size,
                              hipStream_t stream) {
  const float* x  = (const float*)d_in[0];
  const float* ow = (const float*)d_in[1];
  const float* ob = (const float*)d_in[2];
  const float* dw = (const float*)d_in[3];
  float* out = (float*)d_out;

  char* ws = (char*)d_ws;
  size_t w2_bytes   = (size_t)On * W2ROW * 2;           // 384 KB
  size_t woff_bytes = (size_t)32 * Cn * 2;              // 16 KB
  size_t w2_al   = (w2_bytes + 255) & ~(size_t)255;
  size_t woff_al = (woff_bytes + 255) & ~(size_t)255;

  unsigned short* W2   = (unsigned short*)ws;
  unsigned short* Woff = (unsigned short*)(ws + w2_al);
  unsigned short* xbT  = (unsigned short*)(ws + w2_al + woff_al);
  (void)ws_size;

  k_wprep<<<800, 256, 0, stream>>>(dw, ow, W2, Woff);
  k_transpose<<<dim3(256, 4, Bn), 256, 0, stream>>>(x, xbT);
  k_fgemm<<<dim3(128, Bn), 512, 0, stream>>>(xbT, W2, Woff, ob, out);
}